// Round 16
// baseline (195.575 us; speedup 1.0000x reference)
//
#include <hip/hip_runtime.h>
#include <stdint.h>

#define D_MODEL 1024
#define NHEAD 16
#define HDIM 64
#define SEQ 2048
#define NTOK 4096  // B*L
#define KVB 128    // attn key-tile
#define NT (KVB / 16)

typedef unsigned short u16;
typedef float f32x4 __attribute__((ext_vector_type(4)));
typedef __bf16 bf16x8 __attribute__((ext_vector_type(8)));
typedef unsigned int u32x4 __attribute__((ext_vector_type(4)));
typedef u16 u16x4 __attribute__((ext_vector_type(4)));

// Q pre-scale: HD^-0.5 * log2(e); softmax via exp2 is exactly equivalent
#define QSC 0.180336880111117f

__device__ __forceinline__ u16 fcast_bf(float f) {
  __bf16 h = (__bf16)f;  // native RNE cvt
  return __builtin_bit_cast(u16, h);
}

__device__ __forceinline__ float exp2_fast(float x) {
#if __has_builtin(__builtin_amdgcn_exp2f)
  return __builtin_amdgcn_exp2f(x);
#else
  return __expf(x * 0.69314718056f);
#endif
}

__device__ __forceinline__ bf16x8 scale_q(bf16x8 q) {
  bf16x8 r;
#pragma unroll
  for (int i = 0; i < 8; i++) r[i] = (__bf16)((float)q[i] * QSC);
  return r;
}

__device__ __forceinline__ bf16x8 lds_frag(const u16* sm, int off) {
  return *reinterpret_cast<const bf16x8*>(sm + off);
}

// async global->LDS, 16B per lane; lds base must be wave-uniform (HW adds lane*16)
__device__ __forceinline__ void gload_lds16(const u16* g, u16* l) {
  __builtin_amdgcn_global_load_lds((const __attribute__((address_space(1))) void*)g,
                                   (__attribute__((address_space(3))) void*)l, 16, 0, 0);
}

// ---------------- fp32 -> bf16 conversion (all 7 tensors, one launch) ----------------
__global__ void cvt_all_kernel(const float* __restrict__ q, const float* __restrict__ k,
                               const float* __restrict__ v, const float* __restrict__ wq,
                               const float* __restrict__ wk, const float* __restrict__ wv,
                               const float* __restrict__ wo, u16* __restrict__ dst) {
  const int y = blockIdx.y;
  const float* s = y == 0 ? q : (y == 1 ? k : (y == 2 ? v : (y == 3 ? wq :
                   (y == 4 ? wk : (y == 5 ? wv : wo)))));
  const int n4 = y < 3 ? 1048576 : 262144;
  const size_t off4 = y < 3 ? (size_t)y * 1048576 : 3145728 + (size_t)(y - 3) * 262144;
  u16x4* d = reinterpret_cast<u16x4*>(dst) + off4;
  int i = blockIdx.x * blockDim.x + threadIdx.x;
  int stride = gridDim.x * blockDim.x;
  for (; i < n4; i += stride) {
    f32x4 vv = reinterpret_cast<const f32x4*>(s)[i];
    u16x4 o;
    o[0] = fcast_bf(vv[0]); o[1] = fcast_bf(vv[1]);
    o[2] = fcast_bf(vv[2]); o[3] = fcast_bf(vv[3]);
    d[i] = o;
  }
}

// ---------------- GEMM (QKV): C = A @ W^T + bias ----------------
// z = 0/1/2 -> Q/K/V, bf16 out, head-major layouts (V transposed).
// XCD-aware bijective block swizzle (T1).
__global__ __launch_bounds__(256)
void gemm_qkv_kernel(const u16* __restrict__ Abase, const u16* __restrict__ Wbase,
                     const float* __restrict__ b0, const float* __restrict__ b1,
                     const float* __restrict__ b2, u16* __restrict__ obf) {
  const int z = blockIdx.z;
  const u16* A = Abase + (size_t)z * NTOK * D_MODEL;
  const u16* W = Wbase + (size_t)z * D_MODEL * D_MODEL;
  const float* bias = z == 0 ? b0 : (z == 1 ? b1 : b2);
  u16* oz = obf + (size_t)z * NTOK * D_MODEL;

  const int flat = blockIdx.y * 8 + blockIdx.x;  // 256 blocks per z
  const int nf = (flat & 7) * 32 + (flat >> 3);  // bijective XCD chunking
  const int bn0 = (nf & 7) * 128;
  const int bm0 = (nf >> 3) * 128;
  const int tid = threadIdx.x;
  const int lane = tid & 63, wid = tid >> 6;
  const int wm = wid >> 1, wn = wid & 1;
  const int l15 = lane & 15, l4 = lane >> 4;
  const int lrow8 = lane >> 3, lch = lane & 7;

  __shared__ u16 smA[128 * 64];  // linear [row][64]
  __shared__ u16 smB[128 * 64];

  f32x4 acc[4][4];
#pragma unroll
  for (int mi = 0; mi < 4; mi++)
#pragma unroll
    for (int ni = 0; ni < 4; ni++) acc[mi][ni] = f32x4{0.f, 0.f, 0.f, 0.f};

  for (int it = 0; it < D_MODEL / 64; it++) {
    const int k0 = it * 64;
    __syncthreads();
#pragma unroll
    for (int c2 = 0; c2 < 4; c2++) {
      int blk = wid * 4 + c2;
      int base16 = blk * 512;
      int row = blk * 8 + lrow8;
      gload_lds16(A + (size_t)(bm0 + row) * D_MODEL + k0 + lch * 8, &smA[base16]);
      gload_lds16(W + (size_t)(bn0 + row) * D_MODEL + k0 + lch * 8, &smB[base16]);
    }
    __syncthreads();
#pragma unroll
    for (int kk = 0; kk < 2; kk++) {
      bf16x8 af[4], bfv[4];
#pragma unroll
      for (int mi = 0; mi < 4; mi++) {
        int r = wm * 64 + mi * 16 + l15;
        af[mi] = lds_frag(smA, r * 64 + (kk * 4 + l4) * 8);
      }
#pragma unroll
      for (int ni = 0; ni < 4; ni++) {
        int r = wn * 64 + ni * 16 + l15;
        bfv[ni] = lds_frag(smB, r * 64 + (kk * 4 + l4) * 8);
      }
#pragma unroll
      for (int mi = 0; mi < 4; mi++)
#pragma unroll
        for (int ni = 0; ni < 4; ni++)
          acc[mi][ni] = __builtin_amdgcn_mfma_f32_16x16x32_bf16(af[mi], bfv[ni], acc[mi][ni], 0, 0, 0);
    }
  }

#pragma unroll
  for (int mi = 0; mi < 4; mi++) {
#pragma unroll
    for (int ni = 0; ni < 4; ni++) {
      int colg = bn0 + wn * 64 + ni * 16 + l15;
      float bv = bias[colg];
      if (z == 2) {
        // V: [b,h,hd,l] — pack 4 consecutive tokens per 8B store
        int h = colg >> 6, hd = colg & 63;
        int row0 = bm0 + wm * 64 + mi * 16 + l4 * 4;
        int b = row0 >> 11, lq = row0 & 2047;
        u16x4 pk;
#pragma unroll
        for (int j = 0; j < 4; j++) pk[j] = fcast_bf(acc[mi][ni][j] + bv);
        size_t idx = ((size_t)((b * NHEAD + h) * HDIM + hd)) * SEQ + lq;
        *reinterpret_cast<u16x4*>(oz + idx) = pk;
      } else {
#pragma unroll
        for (int j = 0; j < 4; j++) {
          int rowg = bm0 + wm * 64 + mi * 16 + l4 * 4 + j;
          float v = acc[mi][ni][j] + bv;
          int b = rowg >> 11, lq = rowg & 2047;
          int h = colg >> 6, hd = colg & 63;
          oz[((size_t)((b * NHEAD + h) * SEQ + lq)) * HDIM + hd] = fcast_bf(v);
        }
      }
    }
  }
}

// ---------------- flash attention forward ----------------
// 512-thread / 128-q-row blocks; per-wave inner loop is the R4 structure.
// setprio(1) around MFMA clusters (T5 — waves diverge in phase here).
__global__ __launch_bounds__(512)
void attn_kernel(const u16* __restrict__ Qh, const u16* __restrict__ Kh,
                 const u16* __restrict__ Vh, u16* __restrict__ attb,
                 float* __restrict__ m_ws, float* __restrict__ linv_ws) {
  const int qt0 = blockIdx.x * 128;
  const int bh = blockIdx.y;
  const int b = bh >> 4, h = bh & 15;
  const int tid = threadIdx.x;
  const int lane = tid & 63, wid = tid >> 6;  // wid 0..7
  const int l15 = lane & 15, l4 = lane >> 4;

  const u16* Qp = Qh + (size_t)bh * SEQ * HDIM;
  const u16* Kp = Kh + (size_t)bh * SEQ * HDIM;
  const u16* Vp = Vh + (size_t)bh * HDIM * SEQ;

  __shared__ u16 smK[KVB * 64];     // [key][hd], 8 chunks/row, XOR row&7
  __shared__ u16 smV[64 * KVB];     // [hd][key], 16 chunks/row, XOR row&15
  __shared__ u16 smP[8][16 * KVB];  // per-wave P[q][key], 8B-slot XOR 2*q swizzle

  bf16x8 qf[2];
  {
    const u16* qrow = Qp + (size_t)(qt0 + wid * 16 + l15) * HDIM;
    qf[0] = scale_q(*reinterpret_cast<const bf16x8*>(qrow + l4 * 8));
    qf[1] = scale_q(*reinterpret_cast<const bf16x8*>(qrow + 32 + l4 * 8));
  }

  float m = -1e30f, lsum = 0.f;
  f32x4 oacc[4];
#pragma unroll
  for (int d = 0; d < 4; d++) oacc[d] = f32x4{0.f, 0.f, 0.f, 0.f};

  u32x4 rk[2], rv[2];
#pragma unroll
  for (int i = 0; i < 2; i++) {
    int c = i * 512 + tid;  // 0..1023
    rk[i] = *reinterpret_cast<const u32x4*>(Kp + (size_t)(c >> 3) * HDIM + (c & 7) * 8);
    rv[i] = *reinterpret_cast<const u32x4*>(Vp + (size_t)(c >> 4) * SEQ + (c & 15) * 8);
  }

  for (int kt = 0; kt < SEQ / KVB; kt++) {
    __syncthreads();
#pragma unroll
    for (int i = 0; i < 2; i++) {
      int c = i * 512 + tid;
      { int row = c >> 3, ch = c & 7;
        *reinterpret_cast<u32x4*>(&smK[row * 64 + ((ch ^ (row & 7)) * 8)]) = rk[i]; }
      { int row = c >> 4, ch = c & 15;
        *reinterpret_cast<u32x4*>(&smV[row * KVB + ((ch ^ (row & 15)) * 8)]) = rv[i]; }
    }
    __syncthreads();
    if (kt + 1 < SEQ / KVB) {
      int kn = (kt + 1) * KVB;
#pragma unroll
      for (int i = 0; i < 2; i++) {
        int c = i * 512 + tid;
        rk[i] = *reinterpret_cast<const u32x4*>(Kp + (size_t)(kn + (c >> 3)) * HDIM + (c & 7) * 8);
        rv[i] = *reinterpret_cast<const u32x4*>(Vp + (size_t)(c >> 4) * SEQ + kn + (c & 15) * 8);
      }
    }
    // S^T = K·Q (A=K rows=keys, B=Q cols=q)
    f32x4 s[NT];
#pragma unroll
    for (int nt = 0; nt < NT; nt++) s[nt] = f32x4{0.f, 0.f, 0.f, 0.f};
    __builtin_amdgcn_s_setprio(1);
#pragma unroll
    for (int kk = 0; kk < 2; kk++) {
#pragma unroll
      for (int nt = 0; nt < NT; nt++) {
        int r = nt * 16 + l15;
        int ch = (kk * 4 + l4) ^ (r & 7);
        bf16x8 kf = lds_frag(smK, r * 64 + ch * 8);
        s[nt] = __builtin_amdgcn_mfma_f32_16x16x32_bf16(kf, qf[kk], s[nt], 0, 0, 0);
      }
    }
    __builtin_amdgcn_s_setprio(0);
    // softmax (log2 domain): lane holds 32 scores of q-row l15
    float smax = s[0][0];
#pragma unroll
    for (int nt = 0; nt < NT; nt++)
#pragma unroll
      for (int j = 0; j < 4; j++) smax = fmaxf(smax, s[nt][j]);
    smax = fmaxf(smax, __shfl_xor(smax, 16));
    smax = fmaxf(smax, __shfl_xor(smax, 32));
    float mn = fmaxf(m, smax);
    float corr = exp2_fast(m - mn);
    m = mn;
    float ps = 0.f;
#pragma unroll
    for (int nt = 0; nt < NT; nt++) {
      u16x4 pwv;
#pragma unroll
      for (int j = 0; j < 4; j++) {
        float pv = exp2_fast(s[nt][j] - mn);
        ps += pv;
        pwv[j] = fcast_bf(pv);
      }
      int sp = (nt * 4 + l4) ^ (l15 * 2);  // 8B-slot swizzle
      *reinterpret_cast<u16x4*>(&smP[wid][l15 * KVB + sp * 4]) = pwv;
    }
    ps += __shfl_xor(ps, 16);
    ps += __shfl_xor(ps, 32);
    lsum = lsum * corr + ps;
#pragma unroll
    for (int d = 0; d < 4; d++)
#pragma unroll
      for (int j = 0; j < 4; j++) oacc[d][j] *= corr;
    // O^T += V^T · P^T (wave-private smP: in-wave lgkmcnt ordering, no barrier)
    __builtin_amdgcn_s_setprio(1);
#pragma unroll
    for (int kc = 0; kc < 4; kc++) {
      int chp = (kc * 4 + l4) ^ l15;
      bf16x8 pf = lds_frag(smP[wid], l15 * KVB + chp * 8);
#pragma unroll
      for (int d = 0; d < 4; d++) {
        int r = d * 16 + l15;
        int ch = (kc * 4 + l4) ^ (r & 15);
        bf16x8 vf = lds_frag(smV, r * KVB + ch * 8);
        oacc[d] = __builtin_amdgcn_mfma_f32_16x16x32_bf16(vf, pf, oacc[d], 0, 0, 0);
      }
    }
    __builtin_amdgcn_s_setprio(0);
  }

  const float li = 1.f / lsum;
  const int token = qt0 + wid * 16 + l15;
  if (l4 == 0) {
    m_ws[(size_t)bh * SEQ + token] = m;      // log2-domain running max
    linv_ws[(size_t)bh * SEQ + token] = li;
  }
#pragma unroll
  for (int d = 0; d < 4; d++) {
    u16x4 pk;
#pragma unroll
    for (int j = 0; j < 4; j++) pk[j] = fcast_bf(oacc[d][j] * li);
    *reinterpret_cast<u16x4*>(
        attb + ((size_t)(b * SEQ + token)) * D_MODEL + h * HDIM + d * 16 + l4 * 4) = pk;
  }
}

// ---------------- fused tail: out-proj + mean(weights) ----------------
// R16: 256-thread blocks throughout. Mean role re-tiled 512x512t -> 1024x256t
// (q=64: 4 waves x 16 rows; k=128: 2 staged tiles, double-buffered, one
// barrier/head — per-wave phase shape identical to R12's measured optimum).
// Rationale: R13/R15's 2 mean-blocks/CU = only 2 independent barrier domains
// (50% occupancy cap, measured 20%). Now ~5 blocks/CU co-resident -> barrier
// latency hidden by block-level TLP. gemm role = R12 gemm<1> verbatim (bid<256).
__global__ __launch_bounds__(256)
void tail_kernel(const u16* __restrict__ Qh, const u16* __restrict__ Kh,
                 const float* __restrict__ m_ws, const float* __restrict__ linv_ws,
                 float* __restrict__ out1,
                 const u16* __restrict__ attb, const u16* __restrict__ Wo,
                 const float* __restrict__ bo, float* __restrict__ out0) {
  __shared__ u16 smem[16384];  // 32KB: mean [2 buf][2 t][4096] / gemm smA+smB
  const int bid = blockIdx.x;
  const int tid = threadIdx.x;
  const int lane = tid & 63, wid = tid >> 6;
  const int l15 = lane & 15, l4 = lane >> 4;

  if (bid >= 256) {
    // ================= mean role (1024 blocks, 256 threads) =================
    const int mb = bid - 256;
    const int kt0 = (mb & 15) * 128;          // 16 k-tiles of 128
    const int qt0 = ((mb >> 4) & 31) * 64;    // 32 q-tiles of 64
    const int b = mb >> 9;

    f32x4 macc[2][4];
#pragma unroll
    for (int t = 0; t < 2; t++)
#pragma unroll
      for (int nt = 0; nt < 4; nt++) macc[t][nt] = f32x4{0.f, 0.f, 0.f, 0.f};

    const int rbase = qt0 + wid * 16 + l4 * 4;
    const size_t qoff = (size_t)(qt0 + wid * 16 + l15) * HDIM;

    u32x4 rk[4];
    bf16x8 qfa, qfb;
    {
      const u16* Kp0 = Kh + (size_t)(b * NHEAD) * SEQ * HDIM;
#pragma unroll
      for (int i = 0; i < 4; i++) {
        int u = i * 256 + tid;                 // 0..1023 u32x4 units (16KB)
        int t = u >> 9, w = u & 511;
        rk[i] = *reinterpret_cast<const u32x4*>(
            Kp0 + (size_t)(kt0 + t * 64 + (w >> 3)) * HDIM + (w & 7) * 8);
      }
      const u16* Qp0 = Qh + (size_t)(b * NHEAD) * SEQ * HDIM + qoff;
      qfa = scale_q(*reinterpret_cast<const bf16x8*>(Qp0 + l4 * 8));
      qfb = scale_q(*reinterpret_cast<const bf16x8*>(Qp0 + 32 + l4 * 8));
    }

    for (int h = 0; h < NHEAD; h++) {
      const int bh = b * NHEAD + h;
#pragma unroll
      for (int i = 0; i < 4; i++) {
        int u = i * 256 + tid;
        int t = u >> 9, w = u & 511;
        int row = w >> 3, ch = w & 7;
        *reinterpret_cast<u32x4*>(
            &smem[((h & 1) * 2 + t) * 4096 + row * 64 + ((ch ^ (row & 7)) * 8)]) = rk[i];
      }
      __syncthreads();
      // prefetch next head (write(h+2) is after barrier(h+1) -> no race)
      u32x4 rkn[4];
      bf16x8 qfan, qfbn;
      if (h + 1 < NHEAD) {
        const u16* Kp1 = Kh + (size_t)(bh + 1) * SEQ * HDIM;
#pragma unroll
        for (int i = 0; i < 4; i++) {
          int u = i * 256 + tid;
          int t = u >> 9, w = u & 511;
          rkn[i] = *reinterpret_cast<const u32x4*>(
              Kp1 + (size_t)(kt0 + t * 64 + (w >> 3)) * HDIM + (w & 7) * 8);
        }
        const u16* Qp1 = Qh + (size_t)(bh + 1) * SEQ * HDIM + qoff;
        qfan = scale_q(*reinterpret_cast<const bf16x8*>(Qp1 + l4 * 8));
        qfbn = scale_q(*reinterpret_cast<const bf16x8*>(Qp1 + 32 + l4 * 8));
      }
      f32x4 mv = *reinterpret_cast<const f32x4*>(&m_ws[(size_t)bh * SEQ + rbase]);
      f32x4 lv = *reinterpret_cast<const f32x4*>(&linv_ws[(size_t)bh * SEQ + rbase]);
#pragma unroll
      for (int t = 0; t < 2; t++) {
        const u16* kbuf = &smem[((h & 1) * 2 + t) * 4096];
        f32x4 s[4];
#pragma unroll
        for (int nt = 0; nt < 4; nt++) s[nt] = f32x4{0.f, 0.f, 0.f, 0.f};
#pragma unroll
        for (int kk = 0; kk < 2; kk++) {
#pragma unroll
          for (int nt = 0; nt < 4; nt++) {
            int r = nt * 16 + l15;
            int ch = (kk * 4 + l4) ^ (r & 7);
            bf16x8 kf = lds_frag(kbuf, r * 64 + ch * 8);
            s[nt] = __builtin_amdgcn_mfma_f32_16x16x32_bf16(kk == 0 ? qfa : qfb, kf, s[nt], 0, 0, 0);
          }
        }
#pragma unroll
        for (int nt = 0; nt < 4; nt++)
#pragma unroll
          for (int j = 0; j < 4; j++)
            macc[t][nt][j] += exp2_fast(s[nt][j] - mv[j]) * lv[j];
      }
      if (h + 1 < NHEAD) {
#pragma unroll
        for (int i = 0; i < 4; i++) rk[i] = rkn[i];
        qfa = qfan; qfb = qfbn;
      }
    }
    const float invh = 1.f / 16.f;
#pragma unroll
    for (int t = 0; t < 2; t++)
#pragma unroll
      for (int nt = 0; nt < 4; nt++)
#pragma unroll
        for (int j = 0; j < 4; j++)
          out1[((size_t)(b * SEQ + rbase + j)) * SEQ + kt0 + t * 64 + nt * 16 + l15] =
              macc[t][nt][j] * invh;
  } else {
    // ================= output-projection role: out0 = attb @ Wo^T + bo =================
    const int flat = bid;                          // 0..255
    const int nf = (flat & 7) * 32 + (flat >> 3);  // bijective XCD chunking
    const int bn0 = (nf & 7) * 128;
    const int bm0 = (nf >> 3) * 128;
    const int wm = wid >> 1, wn = wid & 1;
    const int lrow8 = lane >> 3, lch = lane & 7;
    u16* smA = smem;           // 128x64
    u16* smB = smem + 8192;    // 128x64

    f32x4 acc[4][4];
#pragma unroll
    for (int mi = 0; mi < 4; mi++)
#pragma unroll
      for (int ni = 0; ni < 4; ni++) acc[mi][ni] = f32x4{0.f, 0.f, 0.f, 0.f};

    for (int it = 0; it < D_MODEL / 64; it++) {
      const int k0 = it * 64;
      __syncthreads();
#pragma unroll
      for (int c2 = 0; c2 < 4; c2++) {
        int blk = wid * 4 + c2;          // 0..15
        int base16 = blk * 512;
        int row = blk * 8 + lrow8;
        gload_lds16(attb + (size_t)(bm0 + row) * D_MODEL + k0 + lch * 8, &smA[base16]);
        gload_lds16(Wo + (size_t)(bn0 + row) * D_MODEL + k0 + lch * 8, &smB[base16]);
      }
      __syncthreads();
#pragma unroll
      for (int kk = 0; kk < 2; kk++) {
        bf16x8 af[4], bfv[4];
#pragma unroll
        for (int mi = 0; mi < 4; mi++) {
          int r = wm * 64 + mi * 16 + l15;
          af[mi] = lds_frag(smA, r * 64 + (kk * 4 + l4) * 8);
        }
#pragma unroll
        for (int ni = 0; ni < 4; ni++) {
          int r = wn * 64 + ni * 16 + l15;
          bfv[ni] = lds_frag(smB, r * 64 + (kk * 4 + l4) * 8);
        }
#pragma unroll
        for (int mi = 0; mi < 4; mi++)
#pragma unroll
          for (int ni = 0; ni < 4; ni++)
            acc[mi][ni] = __builtin_amdgcn_mfma_f32_16x16x32_bf16(af[mi], bfv[ni], acc[mi][ni], 0, 0, 0);
      }
    }

#pragma unroll
    for (int mi = 0; mi < 4; mi++) {
#pragma unroll
      for (int ni = 0; ni < 4; ni++) {
        int colg = bn0 + wn * 64 + ni * 16 + l15;
        float bv = bo[colg];
#pragma unroll
        for (int j = 0; j < 4; j++) {
          int rowg = bm0 + wm * 64 + mi * 16 + l4 * 4 + j;
          out0[(size_t)rowg * D_MODEL + colg] = acc[mi][ni][j] + bv;
        }
      }
    }
  }
}

// ---------------- launch ----------------
extern "C" void kernel_launch(void* const* d_in, const int* in_sizes, int n_in,
                              void* d_out, int out_size, void* d_ws, size_t ws_size,
                              hipStream_t stream) {
  (void)in_sizes; (void)n_in; (void)out_size; (void)ws_size;
  const float* query = (const float*)d_in[0];
  const float* key = (const float*)d_in[1];
  const float* value = (const float*)d_in[2];
  const float* Wq = (const float*)d_in[3];
  const float* bq = (const float*)d_in[4];
  const float* Wk = (const float*)d_in[5];
  const float* bk = (const float*)d_in[6];
  const float* Wv = (const float*)d_in[7];
  const float* bv = (const float*)d_in[8];
  const float* Wo = (const float*)d_in[9];
  const float* bo = (const float*)d_in[10];

  char* ws = (char*)d_ws;
  u16* xb = (u16*)(ws);                   // [3][4096][1024] bf16 inputs (q,k,v)
  u16* wb = (u16*)(ws + 25165824);        // [4][1024][1024] bf16 weights (q,k,v,o)
  u16* Qhp = (u16*)(ws + 33554432);       // Qh,Kh [b,h,l,hd]; Vh [b,h,hd,l]
  u16* attb = (u16*)(ws + 58720256);      // [4096][1024] bf16 attended
  float* m_ws = (float*)(ws + 67108864);  // [32][2048]
  float* linv_ws = (float*)(ws + 67371008);

  float* out0 = (float*)d_out;                      // [2,2048,1024]
  float* out1 = out0 + (size_t)NTOK * D_MODEL;      // [2,2048,2048]

  cvt_all_kernel<<<dim3(256, 7), 256, 0, stream>>>(query, key, value, Wq, Wk, Wv, Wo, xb);

  gemm_qkv_kernel<<<dim3(8, 32, 3), 256, 0, stream>>>(xb, wb, bq, bk, bv, Qhp);
  attn_kernel<<<dim3(16, 32), 512, 0, stream>>>(Qhp, Qhp + 4194304, Qhp + 8388608,
                                                attb, m_ws, linv_ws);
  tail_kernel<<<1280, 256, 0, stream>>>(Qhp, Qhp + 4194304, m_ws, linv_ws, out1,
                                        attb, wb + 3 * 1048576, bo, out0);
}

// Round 17
// 187.329 us; speedup vs baseline: 1.0440x; 1.0440x over previous
//
#include <hip/hip_runtime.h>
#include <stdint.h>

#define D_MODEL 1024
#define NHEAD 16
#define HDIM 64
#define SEQ 2048
#define NTOK 4096  // B*L
#define KVB 128    // attn key-tile
#define NT (KVB / 16)

typedef unsigned short u16;
typedef float f32x4 __attribute__((ext_vector_type(4)));
typedef __bf16 bf16x8 __attribute__((ext_vector_type(8)));
typedef unsigned int u32x4 __attribute__((ext_vector_type(4)));
typedef u16 u16x4 __attribute__((ext_vector_type(4)));

// Q pre-scale: HD^-0.5 * log2(e); softmax via exp2 is exactly equivalent
#define QSC 0.180336880111117f

__device__ __forceinline__ u16 fcast_bf(float f) {
  __bf16 h = (__bf16)f;  // native RNE cvt
  return __builtin_bit_cast(u16, h);
}

__device__ __forceinline__ float exp2_fast(float x) {
#if __has_builtin(__builtin_amdgcn_exp2f)
  return __builtin_amdgcn_exp2f(x);
#else
  return __expf(x * 0.69314718056f);
#endif
}

__device__ __forceinline__ bf16x8 scale_q(bf16x8 q) {
  bf16x8 r;
#pragma unroll
  for (int i = 0; i < 8; i++) r[i] = (__bf16)((float)q[i] * QSC);
  return r;
}

__device__ __forceinline__ bf16x8 lds_frag(const u16* sm, int off) {
  return *reinterpret_cast<const bf16x8*>(sm + off);
}

// async global->LDS, 16B per lane; lds base must be wave-uniform (HW adds lane*16)
__device__ __forceinline__ void gload_lds16(const u16* g, u16* l) {
  __builtin_amdgcn_global_load_lds((const __attribute__((address_space(1))) void*)g,
                                   (__attribute__((address_space(3))) void*)l, 16, 0, 0);
}

// ---------------- fp32 -> bf16 conversion (all 7 tensors, one launch) ----------------
__global__ void cvt_all_kernel(const float* __restrict__ q, const float* __restrict__ k,
                               const float* __restrict__ v, const float* __restrict__ wq,
                               const float* __restrict__ wk, const float* __restrict__ wv,
                               const float* __restrict__ wo, u16* __restrict__ dst) {
  const int y = blockIdx.y;
  const float* s = y == 0 ? q : (y == 1 ? k : (y == 2 ? v : (y == 3 ? wq :
                   (y == 4 ? wk : (y == 5 ? wv : wo)))));
  const int n4 = y < 3 ? 1048576 : 262144;
  const size_t off4 = y < 3 ? (size_t)y * 1048576 : 3145728 + (size_t)(y - 3) * 262144;
  u16x4* d = reinterpret_cast<u16x4*>(dst) + off4;
  int i = blockIdx.x * blockDim.x + threadIdx.x;
  int stride = gridDim.x * blockDim.x;
  for (; i < n4; i += stride) {
    f32x4 vv = reinterpret_cast<const f32x4*>(s)[i];
    u16x4 o;
    o[0] = fcast_bf(vv[0]); o[1] = fcast_bf(vv[1]);
    o[2] = fcast_bf(vv[2]); o[3] = fcast_bf(vv[3]);
    d[i] = o;
  }
}

// ---------------- GEMM (QKV): C = A @ W^T + bias ----------------
// z = 0/1/2 -> Q/K/V, bf16 out, head-major layouts (V transposed).
// XCD-aware bijective block swizzle (T1).
__global__ __launch_bounds__(256)
void gemm_qkv_kernel(const u16* __restrict__ Abase, const u16* __restrict__ Wbase,
                     const float* __restrict__ b0, const float* __restrict__ b1,
                     const float* __restrict__ b2, u16* __restrict__ obf) {
  const int z = blockIdx.z;
  const u16* A = Abase + (size_t)z * NTOK * D_MODEL;
  const u16* W = Wbase + (size_t)z * D_MODEL * D_MODEL;
  const float* bias = z == 0 ? b0 : (z == 1 ? b1 : b2);
  u16* oz = obf + (size_t)z * NTOK * D_MODEL;

  const int flat = blockIdx.y * 8 + blockIdx.x;  // 256 blocks per z
  const int nf = (flat & 7) * 32 + (flat >> 3);  // bijective XCD chunking
  const int bn0 = (nf & 7) * 128;
  const int bm0 = (nf >> 3) * 128;
  const int tid = threadIdx.x;
  const int lane = tid & 63, wid = tid >> 6;
  const int wm = wid >> 1, wn = wid & 1;
  const int l15 = lane & 15, l4 = lane >> 4;
  const int lrow8 = lane >> 3, lch = lane & 7;

  __shared__ u16 smA[128 * 64];  // linear [row][64]
  __shared__ u16 smB[128 * 64];

  f32x4 acc[4][4];
#pragma unroll
  for (int mi = 0; mi < 4; mi++)
#pragma unroll
    for (int ni = 0; ni < 4; ni++) acc[mi][ni] = f32x4{0.f, 0.f, 0.f, 0.f};

  for (int it = 0; it < D_MODEL / 64; it++) {
    const int k0 = it * 64;
    __syncthreads();
#pragma unroll
    for (int c2 = 0; c2 < 4; c2++) {
      int blk = wid * 4 + c2;
      int base16 = blk * 512;
      int row = blk * 8 + lrow8;
      gload_lds16(A + (size_t)(bm0 + row) * D_MODEL + k0 + lch * 8, &smA[base16]);
      gload_lds16(W + (size_t)(bn0 + row) * D_MODEL + k0 + lch * 8, &smB[base16]);
    }
    __syncthreads();
#pragma unroll
    for (int kk = 0; kk < 2; kk++) {
      bf16x8 af[4], bfv[4];
#pragma unroll
      for (int mi = 0; mi < 4; mi++) {
        int r = wm * 64 + mi * 16 + l15;
        af[mi] = lds_frag(smA, r * 64 + (kk * 4 + l4) * 8);
      }
#pragma unroll
      for (int ni = 0; ni < 4; ni++) {
        int r = wn * 64 + ni * 16 + l15;
        bfv[ni] = lds_frag(smB, r * 64 + (kk * 4 + l4) * 8);
      }
#pragma unroll
      for (int mi = 0; mi < 4; mi++)
#pragma unroll
        for (int ni = 0; ni < 4; ni++)
          acc[mi][ni] = __builtin_amdgcn_mfma_f32_16x16x32_bf16(af[mi], bfv[ni], acc[mi][ni], 0, 0, 0);
    }
  }

#pragma unroll
  for (int mi = 0; mi < 4; mi++) {
#pragma unroll
    for (int ni = 0; ni < 4; ni++) {
      int colg = bn0 + wn * 64 + ni * 16 + l15;
      float bv = bias[colg];
      if (z == 2) {
        // V: [b,h,hd,l] — pack 4 consecutive tokens per 8B store
        int h = colg >> 6, hd = colg & 63;
        int row0 = bm0 + wm * 64 + mi * 16 + l4 * 4;
        int b = row0 >> 11, lq = row0 & 2047;
        u16x4 pk;
#pragma unroll
        for (int j = 0; j < 4; j++) pk[j] = fcast_bf(acc[mi][ni][j] + bv);
        size_t idx = ((size_t)((b * NHEAD + h) * HDIM + hd)) * SEQ + lq;
        *reinterpret_cast<u16x4*>(oz + idx) = pk;
      } else {
#pragma unroll
        for (int j = 0; j < 4; j++) {
          int rowg = bm0 + wm * 64 + mi * 16 + l4 * 4 + j;
          float v = acc[mi][ni][j] + bv;
          int b = rowg >> 11, lq = rowg & 2047;
          int h = colg >> 6, hd = colg & 63;
          oz[((size_t)((b * NHEAD + h) * SEQ + lq)) * HDIM + hd] = fcast_bf(v);
        }
      }
    }
  }
}

// ---------------- flash attention forward ----------------
// 512-thread / 128-q-row blocks; per-wave inner loop is the R4 structure.
// setprio(1) around MFMA clusters (T5).
__global__ __launch_bounds__(512)
void attn_kernel(const u16* __restrict__ Qh, const u16* __restrict__ Kh,
                 const u16* __restrict__ Vh, u16* __restrict__ attb,
                 float* __restrict__ m_ws, float* __restrict__ linv_ws) {
  const int qt0 = blockIdx.x * 128;
  const int bh = blockIdx.y;
  const int b = bh >> 4, h = bh & 15;
  const int tid = threadIdx.x;
  const int lane = tid & 63, wid = tid >> 6;  // wid 0..7
  const int l15 = lane & 15, l4 = lane >> 4;

  const u16* Qp = Qh + (size_t)bh * SEQ * HDIM;
  const u16* Kp = Kh + (size_t)bh * SEQ * HDIM;
  const u16* Vp = Vh + (size_t)bh * HDIM * SEQ;

  __shared__ u16 smK[KVB * 64];     // [key][hd], 8 chunks/row, XOR row&7
  __shared__ u16 smV[64 * KVB];     // [hd][key], 16 chunks/row, XOR row&15
  __shared__ u16 smP[8][16 * KVB];  // per-wave P[q][key], 8B-slot XOR 2*q swizzle

  bf16x8 qf[2];
  {
    const u16* qrow = Qp + (size_t)(qt0 + wid * 16 + l15) * HDIM;
    qf[0] = scale_q(*reinterpret_cast<const bf16x8*>(qrow + l4 * 8));
    qf[1] = scale_q(*reinterpret_cast<const bf16x8*>(qrow + 32 + l4 * 8));
  }

  float m = -1e30f, lsum = 0.f;
  f32x4 oacc[4];
#pragma unroll
  for (int d = 0; d < 4; d++) oacc[d] = f32x4{0.f, 0.f, 0.f, 0.f};

  u32x4 rk[2], rv[2];
#pragma unroll
  for (int i = 0; i < 2; i++) {
    int c = i * 512 + tid;  // 0..1023
    rk[i] = *reinterpret_cast<const u32x4*>(Kp + (size_t)(c >> 3) * HDIM + (c & 7) * 8);
    rv[i] = *reinterpret_cast<const u32x4*>(Vp + (size_t)(c >> 4) * SEQ + (c & 15) * 8);
  }

  for (int kt = 0; kt < SEQ / KVB; kt++) {
    __syncthreads();
#pragma unroll
    for (int i = 0; i < 2; i++) {
      int c = i * 512 + tid;
      { int row = c >> 3, ch = c & 7;
        *reinterpret_cast<u32x4*>(&smK[row * 64 + ((ch ^ (row & 7)) * 8)]) = rk[i]; }
      { int row = c >> 4, ch = c & 15;
        *reinterpret_cast<u32x4*>(&smV[row * KVB + ((ch ^ (row & 15)) * 8)]) = rv[i]; }
    }
    __syncthreads();
    if (kt + 1 < SEQ / KVB) {
      int kn = (kt + 1) * KVB;
#pragma unroll
      for (int i = 0; i < 2; i++) {
        int c = i * 512 + tid;
        rk[i] = *reinterpret_cast<const u32x4*>(Kp + (size_t)(kn + (c >> 3)) * HDIM + (c & 7) * 8);
        rv[i] = *reinterpret_cast<const u32x4*>(Vp + (size_t)(c >> 4) * SEQ + kn + (c & 15) * 8);
      }
    }
    // S^T = K·Q (A=K rows=keys, B=Q cols=q)
    f32x4 s[NT];
#pragma unroll
    for (int nt = 0; nt < NT; nt++) s[nt] = f32x4{0.f, 0.f, 0.f, 0.f};
    __builtin_amdgcn_s_setprio(1);
#pragma unroll
    for (int kk = 0; kk < 2; kk++) {
#pragma unroll
      for (int nt = 0; nt < NT; nt++) {
        int r = nt * 16 + l15;
        int ch = (kk * 4 + l4) ^ (r & 7);
        bf16x8 kf = lds_frag(smK, r * 64 + ch * 8);
        s[nt] = __builtin_amdgcn_mfma_f32_16x16x32_bf16(kf, qf[kk], s[nt], 0, 0, 0);
      }
    }
    __builtin_amdgcn_s_setprio(0);
    // softmax (log2 domain): lane holds 32 scores of q-row l15
    float smax = s[0][0];
#pragma unroll
    for (int nt = 0; nt < NT; nt++)
#pragma unroll
      for (int j = 0; j < 4; j++) smax = fmaxf(smax, s[nt][j]);
    smax = fmaxf(smax, __shfl_xor(smax, 16));
    smax = fmaxf(smax, __shfl_xor(smax, 32));
    float mn = fmaxf(m, smax);
    float corr = exp2_fast(m - mn);
    m = mn;
    float ps = 0.f;
#pragma unroll
    for (int nt = 0; nt < NT; nt++) {
      u16x4 pwv;
#pragma unroll
      for (int j = 0; j < 4; j++) {
        float pv = exp2_fast(s[nt][j] - mn);
        ps += pv;
        pwv[j] = fcast_bf(pv);
      }
      int sp = (nt * 4 + l4) ^ (l15 * 2);  // 8B-slot swizzle
      *reinterpret_cast<u16x4*>(&smP[wid][l15 * KVB + sp * 4]) = pwv;
    }
    ps += __shfl_xor(ps, 16);
    ps += __shfl_xor(ps, 32);
    lsum = lsum * corr + ps;
#pragma unroll
    for (int d = 0; d < 4; d++)
#pragma unroll
      for (int j = 0; j < 4; j++) oacc[d][j] *= corr;
    // O^T += V^T · P^T (wave-private smP: in-wave lgkmcnt ordering, no barrier)
    __builtin_amdgcn_s_setprio(1);
#pragma unroll
    for (int kc = 0; kc < 4; kc++) {
      int chp = (kc * 4 + l4) ^ l15;
      bf16x8 pf = lds_frag(smP[wid], l15 * KVB + chp * 8);
#pragma unroll
      for (int d = 0; d < 4; d++) {
        int r = d * 16 + l15;
        int ch = (kc * 4 + l4) ^ (r & 15);
        bf16x8 vf = lds_frag(smV, r * KVB + ch * 8);
        oacc[d] = __builtin_amdgcn_mfma_f32_16x16x32_bf16(vf, pf, oacc[d], 0, 0, 0);
      }
    }
    __builtin_amdgcn_s_setprio(0);
  }

  const float li = 1.f / lsum;
  const int token = qt0 + wid * 16 + l15;
  if (l4 == 0) {
    m_ws[(size_t)bh * SEQ + token] = m;      // log2-domain running max
    linv_ws[(size_t)bh * SEQ + token] = li;
  }
#pragma unroll
  for (int d = 0; d < 4; d++) {
    u16x4 pk;
#pragma unroll
    for (int j = 0; j < 4; j++) pk[j] = fcast_bf(oacc[d][j] * li);
    *reinterpret_cast<u16x4*>(
        attb + ((size_t)(b * SEQ + token)) * D_MODEL + h * HDIM + d * 16 + l4 * 4) = pk;
  }
}

// ---------------- fused tail: out-proj + mean(weights) ----------------
// R17 = R15 structure (best: 184.0us) + depth-2 K/Q register prefetch in the
// mean role (explicit rk0/rk1 ping-pong, head loop manually unrolled by 2 so
// every index is compile-time — rule #20). Loads for head h issue during phase
// h-2 -> 2 full compute phases to cover L2/L3 latency + barrier jitter.
// LDS double-buffer + one barrier/head unchanged (R12 race argument holds).
__global__ __launch_bounds__(512)
void tail_kernel(const u16* __restrict__ Qh, const u16* __restrict__ Kh,
                 const float* __restrict__ m_ws, const float* __restrict__ linv_ws,
                 float* __restrict__ out1,
                 const u16* __restrict__ attb, const u16* __restrict__ Wo,
                 const float* __restrict__ bo, float* __restrict__ out0) {
  __shared__ u16 smem[16384];  // 32KB: mean [2 buf][2 t][4096] / gemm smA+smB
  const int bid = blockIdx.x;
  const int tid = threadIdx.x;
  const int lane = tid & 63, wid = tid >> 6;
  const int l15 = lane & 15, l4 = lane >> 4;

  if (bid >= 256) {
    // ================= mean role =================
    const int mb = bid - 256;
    const int kt0 = (mb & 15) * 128;
    const int qt0 = ((mb >> 4) & 15) * 128;
    const int b = mb >> 8;

    f32x4 macc[2][4];
#pragma unroll
    for (int t = 0; t < 2; t++)
#pragma unroll
      for (int nt = 0; nt < 4; nt++) macc[t][nt] = f32x4{0.f, 0.f, 0.f, 0.f};

    const int rbase = qt0 + wid * 16 + l4 * 4;
    const size_t hstride = (size_t)SEQ * HDIM;
    const int srow = tid >> 3, sch = tid & 7;
    const int soff = srow * 64 + ((sch ^ (srow & 7)) * 8);
    const u16* KhB = Kh + (size_t)(b * NHEAD) * hstride +
                     (size_t)(kt0 + srow) * HDIM + sch * 8;
    const u16* QhB = Qh + (size_t)(b * NHEAD) * hstride +
                     (size_t)(qt0 + wid * 16 + l15) * HDIM + l4 * 8;
    const float* mB = m_ws + (size_t)(b * NHEAD) * SEQ + rbase;
    const float* lB = linv_ws + (size_t)(b * NHEAD) * SEQ + rbase;

    // depth-2 prefetch: rk0/q0 = even head data, rk1/q1 = odd head data
    u32x4 rk0[2], rk1[2];
    bf16x8 qa0, qb0, qa1, qb1;
#pragma unroll
    for (int t = 0; t < 2; t++) {
      rk0[t] = *reinterpret_cast<const u32x4*>(KhB + (size_t)(t * 64) * HDIM);
      rk1[t] = *reinterpret_cast<const u32x4*>(KhB + hstride + (size_t)(t * 64) * HDIM);
    }
    qa0 = *reinterpret_cast<const bf16x8*>(QhB);
    qb0 = *reinterpret_cast<const bf16x8*>(QhB + 32);
    qa1 = *reinterpret_cast<const bf16x8*>(QhB + hstride);
    qb1 = *reinterpret_cast<const bf16x8*>(QhB + hstride + 32);

#pragma unroll 1
    for (int hh = 0; hh < NHEAD; hh += 2) {
      // ---- even phase: h = hh, buffers slot 0/1, state rk0/q0 ----
      {
        const int h = hh;
#pragma unroll
        for (int t = 0; t < 2; t++)
          *reinterpret_cast<u32x4*>(&smem[t * 4096 + soff]) = rk0[t];
        bf16x8 qas = scale_q(qa0), qbs = scale_q(qb0);
        __syncthreads();
        if (h + 2 < NHEAD) {
          const u16* Kp2 = KhB + (size_t)(h + 2) * hstride;
          const u16* Qp2 = QhB + (size_t)(h + 2) * hstride;
#pragma unroll
          for (int t = 0; t < 2; t++)
            rk0[t] = *reinterpret_cast<const u32x4*>(Kp2 + (size_t)(t * 64) * HDIM);
          qa0 = *reinterpret_cast<const bf16x8*>(Qp2);
          qb0 = *reinterpret_cast<const bf16x8*>(Qp2 + 32);
        }
        f32x4 mv = *reinterpret_cast<const f32x4*>(mB + (size_t)h * SEQ);
        f32x4 lv = *reinterpret_cast<const f32x4*>(lB + (size_t)h * SEQ);
#pragma unroll
        for (int t = 0; t < 2; t++) {
          const u16* kbuf = &smem[t * 4096];
          f32x4 s[4];
#pragma unroll
          for (int nt = 0; nt < 4; nt++) s[nt] = f32x4{0.f, 0.f, 0.f, 0.f};
#pragma unroll
          for (int kk = 0; kk < 2; kk++) {
#pragma unroll
            for (int nt = 0; nt < 4; nt++) {
              int r = nt * 16 + l15;
              int ch = (kk * 4 + l4) ^ (r & 7);
              bf16x8 kf = lds_frag(kbuf, r * 64 + ch * 8);
              s[nt] = __builtin_amdgcn_mfma_f32_16x16x32_bf16(kk == 0 ? qas : qbs, kf, s[nt], 0, 0, 0);
            }
          }
#pragma unroll
          for (int nt = 0; nt < 4; nt++)
#pragma unroll
            for (int j = 0; j < 4; j++)
              macc[t][nt][j] += exp2_fast(s[nt][j] - mv[j]) * lv[j];
        }
      }
      // ---- odd phase: h = hh+1, buffers slot 2/3, state rk1/q1 ----
      {
        const int h = hh + 1;
#pragma unroll
        for (int t = 0; t < 2; t++)
          *reinterpret_cast<u32x4*>(&smem[(2 + t) * 4096 + soff]) = rk1[t];
        bf16x8 qas = scale_q(qa1), qbs = scale_q(qb1);
        __syncthreads();
        if (h + 2 < NHEAD) {
          const u16* Kp2 = KhB + (size_t)(h + 2) * hstride;
          const u16* Qp2 = QhB + (size_t)(h + 2) * hstride;
#pragma unroll
          for (int t = 0; t < 2; t++)
            rk1[t] = *reinterpret_cast<const u32x4*>(Kp2 + (size_t)(t * 64) * HDIM);
          qa1 = *reinterpret_cast<const bf16x8*>(Qp2);
          qb1 = *reinterpret_cast<const bf16x8*>(Qp2 + 32);
        }
        f32x4 mv = *reinterpret_cast<const f32x4*>(mB + (size_t)h * SEQ);
        f32x4 lv = *reinterpret_cast<const f32x4*>(lB + (size_t)h * SEQ);
#pragma unroll
        for (int t = 0; t < 2; t++) {
          const u16* kbuf = &smem[(2 + t) * 4096];
          f32x4 s[4];
#pragma unroll
          for (int nt = 0; nt < 4; nt++) s[nt] = f32x4{0.f, 0.f, 0.f, 0.f};
#pragma unroll
          for (int kk = 0; kk < 2; kk++) {
#pragma unroll
            for (int nt = 0; nt < 4; nt++) {
              int r = nt * 16 + l15;
              int ch = (kk * 4 + l4) ^ (r & 7);
              bf16x8 kf = lds_frag(kbuf, r * 64 + ch * 8);
              s[nt] = __builtin_amdgcn_mfma_f32_16x16x32_bf16(kk == 0 ? qas : qbs, kf, s[nt], 0, 0, 0);
            }
          }
#pragma unroll
          for (int nt = 0; nt < 4; nt++)
#pragma unroll
            for (int j = 0; j < 4; j++)
              macc[t][nt][j] += exp2_fast(s[nt][j] - mv[j]) * lv[j];
        }
      }
    }
    const float invh = 1.f / 16.f;
#pragma unroll
    for (int t = 0; t < 2; t++)
#pragma unroll
      for (int nt = 0; nt < 4; nt++)
#pragma unroll
        for (int j = 0; j < 4; j++)
          out1[((size_t)(b * SEQ + rbase + j)) * SEQ + kt0 + t * 64 + nt * 16 + l15] =
              macc[t][nt][j] * invh;
  } else {
    // ================= output-projection role: out0 = attb @ Wo^T + bo =================
    const int flat = bid;                          // 0..255
    const int nf = (flat & 7) * 32 + (flat >> 3);  // bijective XCD chunking
    const int bn0 = (nf & 7) * 128;
    const int bm0 = (nf >> 3) * 128;
    const int wm = wid >> 1, wn = wid & 1;         // wm 0..3: 32-row strip
    const int lrow8 = lane >> 3, lch = lane & 7;
    u16* smA = smem;           // 128x64
    u16* smB = smem + 8192;    // 128x64

    f32x4 acc[2][4];
#pragma unroll
    for (int mi = 0; mi < 2; mi++)
#pragma unroll
      for (int ni = 0; ni < 4; ni++) acc[mi][ni] = f32x4{0.f, 0.f, 0.f, 0.f};

    for (int it = 0; it < D_MODEL / 64; it++) {
      const int k0 = it * 64;
      __syncthreads();
#pragma unroll
      for (int c2 = 0; c2 < 2; c2++) {
        int blk = wid * 2 + c2;          // 0..15
        int base16 = blk * 512;
        int row = blk * 8 + lrow8;
        gload_lds16(attb + (size_t)(bm0 + row) * D_MODEL + k0 + lch * 8, &smA[base16]);
        gload_lds16(Wo + (size_t)(bn0 + row) * D_MODEL + k0 + lch * 8, &smB[base16]);
      }
      __syncthreads();
#pragma unroll
      for (int kk = 0; kk < 2; kk++) {
        bf16x8 af[2], bfv[4];
#pragma unroll
        for (int mi = 0; mi < 2; mi++) {
          int r = wm * 32 + mi * 16 + l15;
          af[mi] = lds_frag(smA, r * 64 + (kk * 4 + l4) * 8);
        }
#pragma unroll
        for (int ni = 0; ni < 4; ni++) {
          int r = wn * 64 + ni * 16 + l15;
          bfv[ni] = lds_frag(smB, r * 64 + (kk * 4 + l4) * 8);
        }
#pragma unroll
        for (int mi = 0; mi < 2; mi++)
#pragma unroll
          for (int ni = 0; ni < 4; ni++)
            acc[mi][ni] = __builtin_amdgcn_mfma_f32_16x16x32_bf16(af[mi], bfv[ni], acc[mi][ni], 0, 0, 0);
      }
    }

#pragma unroll
    for (int mi = 0; mi < 2; mi++) {
#pragma unroll
      for (int ni = 0; ni < 4; ni++) {
        int colg = bn0 + wn * 64 + ni * 16 + l15;
        float bv = bo[colg];
#pragma unroll
        for (int j = 0; j < 4; j++) {
          int rowg = bm0 + wm * 32 + mi * 16 + l4 * 4 + j;
          out0[(size_t)rowg * D_MODEL + colg] = acc[mi][ni][j] + bv;
        }
      }
    }
  }
}

// ---------------- launch ----------------
extern "C" void kernel_launch(void* const* d_in, const int* in_sizes, int n_in,
                              void* d_out, int out_size, void* d_ws, size_t ws_size,
                              hipStream_t stream) {
  (void)in_sizes; (void)n_in; (void)out_size; (void)ws_size;
  const float* query = (const float*)d_in[0];
  const float* key = (const float*)d_in[1];
  const float* value = (const float*)d_in[2];
  const float* Wq = (const float*)d_in[3];
  const float* bq = (const float*)d_in[4];
  const float* Wk = (const float*)d_in[5];
  const float* bk = (const float*)d_in[6];
  const float* Wv = (const float*)d_in[7];
  const float* bv = (const float*)d_in[8];
  const float* Wo = (const float*)d_in[9];
  const float* bo = (const float*)d_in[10];

  char* ws = (char*)d_ws;
  u16* xb = (u16*)(ws);                   // [3][4096][1024] bf16 inputs (q,k,v)
  u16* wb = (u16*)(ws + 25165824);        // [4][1024][1024] bf16 weights (q,k,v,o)
  u16* Qhp = (u16*)(ws + 33554432);       // Qh,Kh [b,h,l,hd]; Vh [b,h,hd,l]
  u16* attb = (u16*)(ws + 58720256);      // [4096][1024] bf16 attended
  float* m_ws = (float*)(ws + 67108864);  // [32][2048]
  float* linv_ws = (float*)(ws + 67371008);

  float* out0 = (float*)d_out;                      // [2,2048,1024]
  float* out1 = out0 + (size_t)NTOK * D_MODEL;      // [2,2048,2048]

  cvt_all_kernel<<<dim3(256, 7), 256, 0, stream>>>(query, key, value, Wq, Wk, Wv, Wo, xb);

  gemm_qkv_kernel<<<dim3(8, 32, 3), 256, 0, stream>>>(xb, wb, bq, bk, bv, Qhp);
  attn_kernel<<<dim3(16, 32), 512, 0, stream>>>(Qhp, Qhp + 4194304, Qhp + 8388608,
                                                attb, m_ws, linv_ws);
  tail_kernel<<<768, 512, 0, stream>>>(Qhp, Qhp + 4194304, m_ws, linv_ws, out1,
                                       attb, wb + 3 * 1048576, bo, out0);
}

// Round 18
// 183.975 us; speedup vs baseline: 1.0631x; 1.0182x over previous
//
#include <hip/hip_runtime.h>
#include <stdint.h>

#define D_MODEL 1024
#define NHEAD 16
#define HDIM 64
#define SEQ 2048
#define NTOK 4096  // B*L
#define KVB 128    // attn key-tile
#define NT (KVB / 16)

typedef unsigned short u16;
typedef float f32x4 __attribute__((ext_vector_type(4)));
typedef __bf16 bf16x8 __attribute__((ext_vector_type(8)));
typedef unsigned int u32x4 __attribute__((ext_vector_type(4)));
typedef u16 u16x4 __attribute__((ext_vector_type(4)));

// Q pre-scale: HD^-0.5 * log2(e); softmax via exp2 is exactly equivalent
#define QSC 0.180336880111117f

__device__ __forceinline__ u16 fcast_bf(float f) {
  __bf16 h = (__bf16)f;  // native RNE cvt
  return __builtin_bit_cast(u16, h);
}

__device__ __forceinline__ float exp2_fast(float x) {
#if __has_builtin(__builtin_amdgcn_exp2f)
  return __builtin_amdgcn_exp2f(x);
#else
  return __expf(x * 0.69314718056f);
#endif
}

__device__ __forceinline__ bf16x8 scale_q(bf16x8 q) {
  bf16x8 r;
#pragma unroll
  for (int i = 0; i < 8; i++) r[i] = (__bf16)((float)q[i] * QSC);
  return r;
}

__device__ __forceinline__ bf16x8 lds_frag(const u16* sm, int off) {
  return *reinterpret_cast<const bf16x8*>(sm + off);
}

// async global->LDS, 16B per lane; lds base must be wave-uniform (HW adds lane*16)
__device__ __forceinline__ void gload_lds16(const u16* g, u16* l) {
  __builtin_amdgcn_global_load_lds((const __attribute__((address_space(1))) void*)g,
                                   (__attribute__((address_space(3))) void*)l, 16, 0, 0);
}

// ---------------- fp32 -> bf16 conversion (all 7 tensors, one launch) ----------------
__global__ void cvt_all_kernel(const float* __restrict__ q, const float* __restrict__ k,
                               const float* __restrict__ v, const float* __restrict__ wq,
                               const float* __restrict__ wk, const float* __restrict__ wv,
                               const float* __restrict__ wo, u16* __restrict__ dst) {
  const int y = blockIdx.y;
  const float* s = y == 0 ? q : (y == 1 ? k : (y == 2 ? v : (y == 3 ? wq :
                   (y == 4 ? wk : (y == 5 ? wv : wo)))));
  const int n4 = y < 3 ? 1048576 : 262144;
  const size_t off4 = y < 3 ? (size_t)y * 1048576 : 3145728 + (size_t)(y - 3) * 262144;
  u16x4* d = reinterpret_cast<u16x4*>(dst) + off4;
  int i = blockIdx.x * blockDim.x + threadIdx.x;
  int stride = gridDim.x * blockDim.x;
  for (; i < n4; i += stride) {
    f32x4 vv = reinterpret_cast<const f32x4*>(s)[i];
    u16x4 o;
    o[0] = fcast_bf(vv[0]); o[1] = fcast_bf(vv[1]);
    o[2] = fcast_bf(vv[2]); o[3] = fcast_bf(vv[3]);
    d[i] = o;
  }
}

// ---------------- GEMM (QKV): C = A @ W^T + bias ----------------
// z = 0/1/2 -> Q/K/V, bf16 out, head-major layouts (V transposed).
// XCD-aware bijective block swizzle (T1).
__global__ __launch_bounds__(256)
void gemm_qkv_kernel(const u16* __restrict__ Abase, const u16* __restrict__ Wbase,
                     const float* __restrict__ b0, const float* __restrict__ b1,
                     const float* __restrict__ b2, u16* __restrict__ obf) {
  const int z = blockIdx.z;
  const u16* A = Abase + (size_t)z * NTOK * D_MODEL;
  const u16* W = Wbase + (size_t)z * D_MODEL * D_MODEL;
  const float* bias = z == 0 ? b0 : (z == 1 ? b1 : b2);
  u16* oz = obf + (size_t)z * NTOK * D_MODEL;

  const int flat = blockIdx.y * 8 + blockIdx.x;  // 256 blocks per z
  const int nf = (flat & 7) * 32 + (flat >> 3);  // bijective XCD chunking
  const int bn0 = (nf & 7) * 128;
  const int bm0 = (nf >> 3) * 128;
  const int tid = threadIdx.x;
  const int lane = tid & 63, wid = tid >> 6;
  const int wm = wid >> 1, wn = wid & 1;
  const int l15 = lane & 15, l4 = lane >> 4;
  const int lrow8 = lane >> 3, lch = lane & 7;

  __shared__ u16 smA[128 * 64];  // linear [row][64]
  __shared__ u16 smB[128 * 64];

  f32x4 acc[4][4];
#pragma unroll
  for (int mi = 0; mi < 4; mi++)
#pragma unroll
    for (int ni = 0; ni < 4; ni++) acc[mi][ni] = f32x4{0.f, 0.f, 0.f, 0.f};

  for (int it = 0; it < D_MODEL / 64; it++) {
    const int k0 = it * 64;
    __syncthreads();
#pragma unroll
    for (int c2 = 0; c2 < 4; c2++) {
      int blk = wid * 4 + c2;
      int base16 = blk * 512;
      int row = blk * 8 + lrow8;
      gload_lds16(A + (size_t)(bm0 + row) * D_MODEL + k0 + lch * 8, &smA[base16]);
      gload_lds16(W + (size_t)(bn0 + row) * D_MODEL + k0 + lch * 8, &smB[base16]);
    }
    __syncthreads();
#pragma unroll
    for (int kk = 0; kk < 2; kk++) {
      bf16x8 af[4], bfv[4];
#pragma unroll
      for (int mi = 0; mi < 4; mi++) {
        int r = wm * 64 + mi * 16 + l15;
        af[mi] = lds_frag(smA, r * 64 + (kk * 4 + l4) * 8);
      }
#pragma unroll
      for (int ni = 0; ni < 4; ni++) {
        int r = wn * 64 + ni * 16 + l15;
        bfv[ni] = lds_frag(smB, r * 64 + (kk * 4 + l4) * 8);
      }
#pragma unroll
      for (int mi = 0; mi < 4; mi++)
#pragma unroll
        for (int ni = 0; ni < 4; ni++)
          acc[mi][ni] = __builtin_amdgcn_mfma_f32_16x16x32_bf16(af[mi], bfv[ni], acc[mi][ni], 0, 0, 0);
    }
  }

#pragma unroll
  for (int mi = 0; mi < 4; mi++) {
#pragma unroll
    for (int ni = 0; ni < 4; ni++) {
      int colg = bn0 + wn * 64 + ni * 16 + l15;
      float bv = bias[colg];
      if (z == 2) {
        // V: [b,h,hd,l] — pack 4 consecutive tokens per 8B store
        int h = colg >> 6, hd = colg & 63;
        int row0 = bm0 + wm * 64 + mi * 16 + l4 * 4;
        int b = row0 >> 11, lq = row0 & 2047;
        u16x4 pk;
#pragma unroll
        for (int j = 0; j < 4; j++) pk[j] = fcast_bf(acc[mi][ni][j] + bv);
        size_t idx = ((size_t)((b * NHEAD + h) * HDIM + hd)) * SEQ + lq;
        *reinterpret_cast<u16x4*>(oz + idx) = pk;
      } else {
#pragma unroll
        for (int j = 0; j < 4; j++) {
          int rowg = bm0 + wm * 64 + mi * 16 + l4 * 4 + j;
          float v = acc[mi][ni][j] + bv;
          int b = rowg >> 11, lq = rowg & 2047;
          int h = colg >> 6, hd = colg & 63;
          oz[((size_t)((b * NHEAD + h) * SEQ + lq)) * HDIM + hd] = fcast_bf(v);
        }
      }
    }
  }
}

// ---------------- flash attention forward ----------------
// 512-thread / 128-q-row blocks; per-wave inner loop is the R4 structure.
// setprio(1) around MFMA clusters (T5).
__global__ __launch_bounds__(512)
void attn_kernel(const u16* __restrict__ Qh, const u16* __restrict__ Kh,
                 const u16* __restrict__ Vh, u16* __restrict__ attb,
                 float* __restrict__ m_ws, float* __restrict__ linv_ws) {
  const int qt0 = blockIdx.x * 128;
  const int bh = blockIdx.y;
  const int b = bh >> 4, h = bh & 15;
  const int tid = threadIdx.x;
  const int lane = tid & 63, wid = tid >> 6;  // wid 0..7
  const int l15 = lane & 15, l4 = lane >> 4;

  const u16* Qp = Qh + (size_t)bh * SEQ * HDIM;
  const u16* Kp = Kh + (size_t)bh * SEQ * HDIM;
  const u16* Vp = Vh + (size_t)bh * HDIM * SEQ;

  __shared__ u16 smK[KVB * 64];     // [key][hd], 8 chunks/row, XOR row&7
  __shared__ u16 smV[64 * KVB];     // [hd][key], 16 chunks/row, XOR row&15
  __shared__ u16 smP[8][16 * KVB];  // per-wave P[q][key], 8B-slot XOR 2*q swizzle

  bf16x8 qf[2];
  {
    const u16* qrow = Qp + (size_t)(qt0 + wid * 16 + l15) * HDIM;
    qf[0] = scale_q(*reinterpret_cast<const bf16x8*>(qrow + l4 * 8));
    qf[1] = scale_q(*reinterpret_cast<const bf16x8*>(qrow + 32 + l4 * 8));
  }

  float m = -1e30f, lsum = 0.f;
  f32x4 oacc[4];
#pragma unroll
  for (int d = 0; d < 4; d++) oacc[d] = f32x4{0.f, 0.f, 0.f, 0.f};

  u32x4 rk[2], rv[2];
#pragma unroll
  for (int i = 0; i < 2; i++) {
    int c = i * 512 + tid;  // 0..1023
    rk[i] = *reinterpret_cast<const u32x4*>(Kp + (size_t)(c >> 3) * HDIM + (c & 7) * 8);
    rv[i] = *reinterpret_cast<const u32x4*>(Vp + (size_t)(c >> 4) * SEQ + (c & 15) * 8);
  }

  for (int kt = 0; kt < SEQ / KVB; kt++) {
    __syncthreads();
#pragma unroll
    for (int i = 0; i < 2; i++) {
      int c = i * 512 + tid;
      { int row = c >> 3, ch = c & 7;
        *reinterpret_cast<u32x4*>(&smK[row * 64 + ((ch ^ (row & 7)) * 8)]) = rk[i]; }
      { int row = c >> 4, ch = c & 15;
        *reinterpret_cast<u32x4*>(&smV[row * KVB + ((ch ^ (row & 15)) * 8)]) = rv[i]; }
    }
    __syncthreads();
    if (kt + 1 < SEQ / KVB) {
      int kn = (kt + 1) * KVB;
#pragma unroll
      for (int i = 0; i < 2; i++) {
        int c = i * 512 + tid;
        rk[i] = *reinterpret_cast<const u32x4*>(Kp + (size_t)(kn + (c >> 3)) * HDIM + (c & 7) * 8);
        rv[i] = *reinterpret_cast<const u32x4*>(Vp + (size_t)(c >> 4) * SEQ + kn + (c & 15) * 8);
      }
    }
    // S^T = K·Q (A=K rows=keys, B=Q cols=q)
    f32x4 s[NT];
#pragma unroll
    for (int nt = 0; nt < NT; nt++) s[nt] = f32x4{0.f, 0.f, 0.f, 0.f};
    __builtin_amdgcn_s_setprio(1);
#pragma unroll
    for (int kk = 0; kk < 2; kk++) {
#pragma unroll
      for (int nt = 0; nt < NT; nt++) {
        int r = nt * 16 + l15;
        int ch = (kk * 4 + l4) ^ (r & 7);
        bf16x8 kf = lds_frag(smK, r * 64 + ch * 8);
        s[nt] = __builtin_amdgcn_mfma_f32_16x16x32_bf16(kf, qf[kk], s[nt], 0, 0, 0);
      }
    }
    __builtin_amdgcn_s_setprio(0);
    // softmax (log2 domain): lane holds 32 scores of q-row l15
    float smax = s[0][0];
#pragma unroll
    for (int nt = 0; nt < NT; nt++)
#pragma unroll
      for (int j = 0; j < 4; j++) smax = fmaxf(smax, s[nt][j]);
    smax = fmaxf(smax, __shfl_xor(smax, 16));
    smax = fmaxf(smax, __shfl_xor(smax, 32));
    float mn = fmaxf(m, smax);
    float corr = exp2_fast(m - mn);
    m = mn;
    float ps = 0.f;
#pragma unroll
    for (int nt = 0; nt < NT; nt++) {
      u16x4 pwv;
#pragma unroll
      for (int j = 0; j < 4; j++) {
        float pv = exp2_fast(s[nt][j] - mn);
        ps += pv;
        pwv[j] = fcast_bf(pv);
      }
      int sp = (nt * 4 + l4) ^ (l15 * 2);  // 8B-slot swizzle
      *reinterpret_cast<u16x4*>(&smP[wid][l15 * KVB + sp * 4]) = pwv;
    }
    ps += __shfl_xor(ps, 16);
    ps += __shfl_xor(ps, 32);
    lsum = lsum * corr + ps;
#pragma unroll
    for (int d = 0; d < 4; d++)
#pragma unroll
      for (int j = 0; j < 4; j++) oacc[d][j] *= corr;
    // O^T += V^T · P^T (wave-private smP: in-wave lgkmcnt ordering, no barrier)
    __builtin_amdgcn_s_setprio(1);
#pragma unroll
    for (int kc = 0; kc < 4; kc++) {
      int chp = (kc * 4 + l4) ^ l15;
      bf16x8 pf = lds_frag(smP[wid], l15 * KVB + chp * 8);
#pragma unroll
      for (int d = 0; d < 4; d++) {
        int r = d * 16 + l15;
        int ch = (kc * 4 + l4) ^ (r & 15);
        bf16x8 vf = lds_frag(smV, r * KVB + ch * 8);
        oacc[d] = __builtin_amdgcn_mfma_f32_16x16x32_bf16(vf, pf, oacc[d], 0, 0, 0);
      }
    }
    __builtin_amdgcn_s_setprio(0);
  }

  const float li = 1.f / lsum;
  const int token = qt0 + wid * 16 + l15;
  if (l4 == 0) {
    m_ws[(size_t)bh * SEQ + token] = m;      // log2-domain running max
    linv_ws[(size_t)bh * SEQ + token] = li;
  }
#pragma unroll
  for (int d = 0; d < 4; d++) {
    u16x4 pk;
#pragma unroll
    for (int j = 0; j < 4; j++) pk[j] = fcast_bf(oacc[d][j] * li);
    *reinterpret_cast<u16x4*>(
        attb + ((size_t)(b * SEQ + token)) * D_MODEL + h * HDIM + d * 16 + l4 * 4) = pk;
  }
}

// ---------------- fused tail: out-proj + mean(weights) ----------------
// R18 = R15 exactly (measured best 184.0us). gemm role bid<256; mean role
// bid 256..767 = R12 LDS-staged double-buffer, depth-1 prefetch, one
// barrier/head — the measured optimum across 7 structural variants.
__global__ __launch_bounds__(512)
void tail_kernel(const u16* __restrict__ Qh, const u16* __restrict__ Kh,
                 const float* __restrict__ m_ws, const float* __restrict__ linv_ws,
                 float* __restrict__ out1,
                 const u16* __restrict__ attb, const u16* __restrict__ Wo,
                 const float* __restrict__ bo, float* __restrict__ out0) {
  __shared__ u16 smem[16384];  // 32KB: mean [2][2][4096] / gemm smA+smB
  const int bid = blockIdx.x;
  const int tid = threadIdx.x;
  const int lane = tid & 63, wid = tid >> 6;
  const int l15 = lane & 15, l4 = lane >> 4;

  if (bid >= 256) {
    // ================= mean role =================
    const int mb = bid - 256;
    const int kt0 = (mb & 15) * 128;
    const int qt0 = ((mb >> 4) & 15) * 128;
    const int b = mb >> 8;

    f32x4 macc[2][4];
#pragma unroll
    for (int t = 0; t < 2; t++)
#pragma unroll
      for (int nt = 0; nt < 4; nt++) macc[t][nt] = f32x4{0.f, 0.f, 0.f, 0.f};

    const int rbase = qt0 + wid * 16 + l4 * 4;
    const size_t qoff = (size_t)(qt0 + wid * 16 + l15) * HDIM;
    const int srow = tid >> 3, sch = tid & 7;
    const int soff = srow * 64 + ((sch ^ (srow & 7)) * 8);

    u32x4 rk[2];
    bf16x8 qfa, qfb;
    {
      const u16* Kp0 = Kh + (size_t)(b * NHEAD) * SEQ * HDIM;
#pragma unroll
      for (int t = 0; t < 2; t++)
        rk[t] = *reinterpret_cast<const u32x4*>(Kp0 + (size_t)(kt0 + t * 64 + srow) * HDIM + sch * 8);
      const u16* Qp0 = Qh + (size_t)(b * NHEAD) * SEQ * HDIM + qoff;
      qfa = scale_q(*reinterpret_cast<const bf16x8*>(Qp0 + l4 * 8));
      qfb = scale_q(*reinterpret_cast<const bf16x8*>(Qp0 + 32 + l4 * 8));
    }

    for (int h = 0; h < NHEAD; h++) {
      const int bh = b * NHEAD + h;
#pragma unroll
      for (int t = 0; t < 2; t++)
        *reinterpret_cast<u32x4*>(&smem[((h & 1) * 2 + t) * 4096 + soff]) = rk[t];
      __syncthreads();
      u32x4 rkn[2];
      bf16x8 qfan, qfbn;
      if (h + 1 < NHEAD) {
        const u16* Kp1 = Kh + (size_t)(bh + 1) * SEQ * HDIM;
#pragma unroll
        for (int t = 0; t < 2; t++)
          rkn[t] = *reinterpret_cast<const u32x4*>(Kp1 + (size_t)(kt0 + t * 64 + srow) * HDIM + sch * 8);
        const u16* Qp1 = Qh + (size_t)(bh + 1) * SEQ * HDIM + qoff;
        qfan = scale_q(*reinterpret_cast<const bf16x8*>(Qp1 + l4 * 8));
        qfbn = scale_q(*reinterpret_cast<const bf16x8*>(Qp1 + 32 + l4 * 8));
      }
      f32x4 mv = *reinterpret_cast<const f32x4*>(&m_ws[(size_t)bh * SEQ + rbase]);
      f32x4 lv = *reinterpret_cast<const f32x4*>(&linv_ws[(size_t)bh * SEQ + rbase]);
#pragma unroll
      for (int t = 0; t < 2; t++) {
        const u16* kbuf = &smem[((h & 1) * 2 + t) * 4096];
        f32x4 s[4];
#pragma unroll
        for (int nt = 0; nt < 4; nt++) s[nt] = f32x4{0.f, 0.f, 0.f, 0.f};
#pragma unroll
        for (int kk = 0; kk < 2; kk++) {
#pragma unroll
          for (int nt = 0; nt < 4; nt++) {
            int r = nt * 16 + l15;
            int ch = (kk * 4 + l4) ^ (r & 7);
            bf16x8 kf = lds_frag(kbuf, r * 64 + ch * 8);
            s[nt] = __builtin_amdgcn_mfma_f32_16x16x32_bf16(kk == 0 ? qfa : qfb, kf, s[nt], 0, 0, 0);
          }
        }
#pragma unroll
        for (int nt = 0; nt < 4; nt++)
#pragma unroll
          for (int j = 0; j < 4; j++)
            macc[t][nt][j] += exp2_fast(s[nt][j] - mv[j]) * lv[j];
      }
      if (h + 1 < NHEAD) {
        rk[0] = rkn[0]; rk[1] = rkn[1];
        qfa = qfan; qfb = qfbn;
      }
    }
    const float invh = 1.f / 16.f;
#pragma unroll
    for (int t = 0; t < 2; t++)
#pragma unroll
      for (int nt = 0; nt < 4; nt++)
#pragma unroll
        for (int j = 0; j < 4; j++)
          out1[((size_t)(b * SEQ + rbase + j)) * SEQ + kt0 + t * 64 + nt * 16 + l15] =
              macc[t][nt][j] * invh;
  } else {
    // ================= output-projection role: out0 = attb @ Wo^T + bo =================
    const int flat = bid;                          // 0..255
    const int nf = (flat & 7) * 32 + (flat >> 3);  // bijective XCD chunking
    const int bn0 = (nf & 7) * 128;
    const int bm0 = (nf >> 3) * 128;
    const int wm = wid >> 1, wn = wid & 1;         // wm 0..3: 32-row strip
    const int lrow8 = lane >> 3, lch = lane & 7;
    u16* smA = smem;           // 128x64
    u16* smB = smem + 8192;    // 128x64

    f32x4 acc[2][4];
#pragma unroll
    for (int mi = 0; mi < 2; mi++)
#pragma unroll
      for (int ni = 0; ni < 4; ni++) acc[mi][ni] = f32x4{0.f, 0.f, 0.f, 0.f};

    for (int it = 0; it < D_MODEL / 64; it++) {
      const int k0 = it * 64;
      __syncthreads();
#pragma unroll
      for (int c2 = 0; c2 < 2; c2++) {
        int blk = wid * 2 + c2;          // 0..15
        int base16 = blk * 512;
        int row = blk * 8 + lrow8;
        gload_lds16(attb + (size_t)(bm0 + row) * D_MODEL + k0 + lch * 8, &smA[base16]);
        gload_lds16(Wo + (size_t)(bn0 + row) * D_MODEL + k0 + lch * 8, &smB[base16]);
      }
      __syncthreads();
#pragma unroll
      for (int kk = 0; kk < 2; kk++) {
        bf16x8 af[2], bfv[4];
#pragma unroll
        for (int mi = 0; mi < 2; mi++) {
          int r = wm * 32 + mi * 16 + l15;
          af[mi] = lds_frag(smA, r * 64 + (kk * 4 + l4) * 8);
        }
#pragma unroll
        for (int ni = 0; ni < 4; ni++) {
          int r = wn * 64 + ni * 16 + l15;
          bfv[ni] = lds_frag(smB, r * 64 + (kk * 4 + l4) * 8);
        }
#pragma unroll
        for (int mi = 0; mi < 2; mi++)
#pragma unroll
          for (int ni = 0; ni < 4; ni++)
            acc[mi][ni] = __builtin_amdgcn_mfma_f32_16x16x32_bf16(af[mi], bfv[ni], acc[mi][ni], 0, 0, 0);
      }
    }

#pragma unroll
    for (int mi = 0; mi < 2; mi++) {
#pragma unroll
      for (int ni = 0; ni < 4; ni++) {
        int colg = bn0 + wn * 64 + ni * 16 + l15;
        float bv = bo[colg];
#pragma unroll
        for (int j = 0; j < 4; j++) {
          int rowg = bm0 + wm * 32 + mi * 16 + l4 * 4 + j;
          out0[(size_t)rowg * D_MODEL + colg] = acc[mi][ni][j] + bv;
        }
      }
    }
  }
}

// ---------------- launch ----------------
extern "C" void kernel_launch(void* const* d_in, const int* in_sizes, int n_in,
                              void* d_out, int out_size, void* d_ws, size_t ws_size,
                              hipStream_t stream) {
  (void)in_sizes; (void)n_in; (void)out_size; (void)ws_size;
  const float* query = (const float*)d_in[0];
  const float* key = (const float*)d_in[1];
  const float* value = (const float*)d_in[2];
  const float* Wq = (const float*)d_in[3];
  const float* bq = (const float*)d_in[4];
  const float* Wk = (const float*)d_in[5];
  const float* bk = (const float*)d_in[6];
  const float* Wv = (const float*)d_in[7];
  const float* bv = (const float*)d_in[8];
  const float* Wo = (const float*)d_in[9];
  const float* bo = (const float*)d_in[10];

  char* ws = (char*)d_ws;
  u16* xb = (u16*)(ws);                   // [3][4096][1024] bf16 inputs (q,k,v)
  u16* wb = (u16*)(ws + 25165824);        // [4][1024][1024] bf16 weights (q,k,v,o)
  u16* Qhp = (u16*)(ws + 33554432);       // Qh,Kh [b,h,l,hd]; Vh [b,h,hd,l]
  u16* attb = (u16*)(ws + 58720256);      // [4096][1024] bf16 attended
  float* m_ws = (float*)(ws + 67108864);  // [32][2048]
  float* linv_ws = (float*)(ws + 67371008);

  float* out0 = (float*)d_out;                      // [2,2048,1024]
  float* out1 = out0 + (size_t)NTOK * D_MODEL;      // [2,2048,2048]

  cvt_all_kernel<<<dim3(512, 7), 256, 0, stream>>>(query, key, value, Wq, Wk, Wv, Wo, xb);

  gemm_qkv_kernel<<<dim3(8, 32, 3), 256, 0, stream>>>(xb, wb, bq, bk, bv, Qhp);
  attn_kernel<<<dim3(16, 32), 512, 0, stream>>>(Qhp, Qhp + 4194304, Qhp + 8388608,
                                                attb, m_ws, linv_ws);
  tail_kernel<<<768, 512, 0, stream>>>(Qhp, Qhp + 4194304, m_ws, linv_ws, out1,
                                       attb, wb + 3 * 1048576, bo, out0);
}